// Round 4
// baseline (219.239 us; speedup 1.0000x reference)
//
#include <hip/hip_runtime.h>
#include <hip/hip_bf16.h>

#define ETA_MIN 2.302585092994046f  // log(10)
#define ETA_MAX 20.0f

// Native clang vector type — HIP's float4 is a struct and is rejected by
// __builtin_nontemporal_load/store; ext_vector_type(4) float is accepted.
typedef float v4f __attribute__((ext_vector_type(4)));

#define VPT 4  // v4f elements per thread (64 B/thread) — 4 independent loads in flight per lane

// Elementwise: w_i = (loss_i > eta) ? 0 : 1 - loss_i/eta, eta = clamp(eta_value[0], ETA_MIN, ETA_MAX)
// Memory-bound: 256 MB mandatory traffic; copy-µbench ceiling 6.29 TB/s -> ~41 us.
// nt load/store (single-touch streams, no L2 retention value) + 4x coarsening
// for memory-level parallelism (one outstanding vmcnt req/wave was the limiter).
__global__ __launch_bounds__(256) void Weightfun_78374563217418_kernel(
        const v4f* __restrict__ loss,
        const float* __restrict__ eta_ptr,
        v4f* __restrict__ out,
        int n4) {
    // block handles VPT*256 consecutive v4f; each load block-strided -> fully coalesced
    int base = blockIdx.x * (blockDim.x * VPT) + threadIdx.x;

    float eta = eta_ptr[0];
    eta = fminf(fmaxf(eta, ETA_MIN), ETA_MAX);
    float inv_eta = 1.0f / eta;

    v4f l[VPT];
    int idx[VPT];
#pragma unroll
    for (int j = 0; j < VPT; ++j) {
        idx[j] = base + j * blockDim.x;
        l[j] = __builtin_nontemporal_load(&loss[idx[j]]);  // 4 independent vmem reqs in flight
    }
#pragma unroll
    for (int j = 0; j < VPT; ++j) {
        v4f w;
        w.x = (l[j].x > eta) ? 0.0f : fmaf(-l[j].x, inv_eta, 1.0f);
        w.y = (l[j].y > eta) ? 0.0f : fmaf(-l[j].y, inv_eta, 1.0f);
        w.z = (l[j].z > eta) ? 0.0f : fmaf(-l[j].z, inv_eta, 1.0f);
        w.w = (l[j].w > eta) ? 0.0f : fmaf(-l[j].w, inv_eta, 1.0f);
        __builtin_nontemporal_store(w, &out[idx[j]]);
    }
}

extern "C" void kernel_launch(void* const* d_in, const int* in_sizes, int n_in,
                              void* d_out, int out_size, void* d_ws, size_t ws_size,
                              hipStream_t stream) {
    const v4f*   loss = (const v4f*)d_in[0];
    const float* eta  = (const float*)d_in[1];
    v4f*         out  = (v4f*)d_out;

    int n  = in_sizes[0];              // 33554432 = 2^25, divisible by 4*256*VPT
    int n4 = n / 4;                    // 8388608 v4f elements
    int block = 256;
    int grid  = n4 / (block * VPT);    // 8192 blocks = 32 blocks/CU — still saturating

    Weightfun_78374563217418_kernel<<<grid, block, 0, stream>>>(loss, eta, out, n4);
}

// Round 5
// 218.131 us; speedup vs baseline: 1.0051x; 1.0051x over previous
//
#include <hip/hip_runtime.h>
#include <hip/hip_bf16.h>

#define ETA_MIN 2.302585092994046f  // log(10)
#define ETA_MAX 20.0f

// Native clang vector type — HIP's float4 is a struct and is rejected by
// __builtin_nontemporal_load/store; ext_vector_type(4) float is accepted.
typedef float v4f __attribute__((ext_vector_type(4)));

// Elementwise: w_i = (loss_i > eta) ? 0 : 1 - loss_i/eta, eta = clamp(eta_value[0], ETA_MIN, ETA_MAX)
// Memory-bound: 256 MiB mandatory traffic (fp32 in + fp32 out, zero reuse).
// Best-measured config (R3): VPT=1, 16 B/lane coalesced, nt on both streams
// (single-touch, no L2 retention value). R4 showed 4x coarsening is neutral-to-
// negative: MLP is not the limiter; mixed read+write HBM turnaround is.
__global__ __launch_bounds__(256) void Weightfun_78374563217418_kernel(
        const v4f* __restrict__ loss,
        const float* __restrict__ eta_ptr,
        v4f* __restrict__ out,
        int n4) {
    int i = blockIdx.x * blockDim.x + threadIdx.x;
    // scalar broadcast load; clamped per reference
    float eta = eta_ptr[0];
    eta = fminf(fmaxf(eta, ETA_MIN), ETA_MAX);
    float inv_eta = 1.0f / eta;  // one precise divide per thread

    if (i < n4) {
        v4f l = __builtin_nontemporal_load(&loss[i]);
        v4f w;
        w.x = (l.x > eta) ? 0.0f : fmaf(-l.x, inv_eta, 1.0f);
        w.y = (l.y > eta) ? 0.0f : fmaf(-l.y, inv_eta, 1.0f);
        w.z = (l.z > eta) ? 0.0f : fmaf(-l.z, inv_eta, 1.0f);
        w.w = (l.w > eta) ? 0.0f : fmaf(-l.w, inv_eta, 1.0f);
        __builtin_nontemporal_store(w, &out[i]);
    }
}

extern "C" void kernel_launch(void* const* d_in, const int* in_sizes, int n_in,
                              void* d_out, int out_size, void* d_ws, size_t ws_size,
                              hipStream_t stream) {
    const v4f*   loss = (const v4f*)d_in[0];
    const float* eta  = (const float*)d_in[1];
    v4f*         out  = (v4f*)d_out;

    int n  = in_sizes[0];          // 33554432 = 2^25, divisible by 4
    int n4 = n / 4;                // 8388608 v4f elements
    int block = 256;
    int grid  = (n4 + block - 1) / block;  // 32768 blocks — saturates 256 CUs

    Weightfun_78374563217418_kernel<<<grid, block, 0, stream>>>(loss, eta, out, n4);
}